// Round 1
// baseline (341.580 us; speedup 1.0000x reference)
//
#include <hip/hip_runtime.h>
#include <math.h>

#define NTHREADS 1024

constexpr int An = 3;
constexpr int Wd = 52;
constexpr int HWn = 2704;        // 52*52
constexpr int ATT = 85;
constexpr int CH = 208;          // 4 grid rows per decode tile
constexpr int PITCH = 209;       // odd -> LDS bank stride 17, conflict-free
constexpr int CHUNKS = 13;       // 2704 / 208
constexpr int BAn = 96;          // 32 batches * 3 anchors
constexpr int DEC_BLOCKS = BAn * CHUNKS;   // 1248
constexpr int NC = An * HWn;     // 8112 candidates (batch 0)
constexpr int NSORT = 8192;
constexpr int OUT_DEC = 32 * NC * ATT;     // 22064640 floats (decode output)
constexpr float NEGV = -1.0e9f;

__device__ __forceinline__ float sig_(float x) {
    return 1.0f / (1.0f + expf(-x));
}

__global__ void __launch_bounds__(NTHREADS)
yolo_fused(const float* __restrict__ in, const float* __restrict__ anc,
           float* __restrict__ out, float* __restrict__ ws)
{
    extern __shared__ float smem[];
    const int tid = threadIdx.x;

    if (blockIdx.x != 0) {
        // ======================= decode =======================
        // channel base for (b,a) is 85*(3b+a) = 85*ba since 255 = 3*85
        const int bi    = (int)blockIdx.x - 1;
        const int chunk = bi % CHUNKS;
        const int ba    = bi / CHUNKS;
        const int a     = ba % An;
        const float anc_w = anc[(6 + a) * 2 + 0] * 0.125f;   // /stride(=8), exact
        const float anc_h = anc[(6 + a) * 2 + 1] * 0.125f;
        const int pos0  = chunk * CH;
        const float* src = in + (size_t)ba * 85 * HWn + pos0;

        // load + transform: rows contiguous -> coalesced; LDS stride-1 writes
        for (int i = tid; i < ATT * CH; i += NTHREADS) {
            const int attr = i / CH;
            const int p    = i - attr * CH;
            const int pos  = pos0 + p;
            const float x  = src[(size_t)attr * HWn + p];
            float v;
            if (attr >= 4)      v = sig_(x);
            else if (attr == 0) v = (sig_(x) + (float)(pos % Wd)) / 52.0f;
            else if (attr == 1) v = (sig_(x) + (float)(pos / Wd)) / 52.0f;
            else if (attr == 2) v = expf(x) * anc_w / 52.0f;
            else                v = expf(x) * anc_h / 52.0f;
            smem[attr * PITCH + p] = v;
        }
        __syncthreads();

        // store: fully contiguous global writes; LDS stride 209 (bank step 17)
        float* dst = out + ((size_t)ba * HWn + pos0) * ATT;
        for (int f = tid; f < CH * ATT; f += NTHREADS) {
            const int p    = f / ATT;
            const int attr = f - p * ATT;
            dst[f] = smem[attr * PITCH + p];
        }
        return;
    }

    // ======================= NMS (block 0, batch 0) =======================
    float* ks       = smem;                         // [8192] scores
    int*   ki       = (int*)(smem + NSORT);         // [8192] candidate index
    float* kept     = smem + 2 * NSORT;             // [100*4] kept oboxes
    float* detstage = smem + 2 * NSORT + 416;       // [100*7] staged det rows
    int*   meta     = (int*)(smem + 2 * NSORT + 416 + 704); // [0]=V, [1]=nk

    for (int i = tid; i < NSORT; i += NTHREADS) { ks[i] = NEGV; ki[i] = i; }
    if (tid == 0) meta[0] = 0;
    __syncthreads();

    // ---- prep: compute score/corners/class per candidate, payload -> ws ----
    for (int k = 0; k < 8; ++k) {
        const int n = tid + k * NTHREADS;
        if (n < NC) {
            const int a   = n / HWn;
            const int pos = n - a * HWn;
            const float* p = in + (size_t)a * 85 * HWn + pos;  // batch 0
            const float tx = p[0];
            const float ty = p[HWn];
            const float tw = p[2 * HWn];
            const float th = p[3 * HWn];
            const float tc = p[4 * HWn];
            float m = -3.0e38f; int cp = 0;
            for (int j = 0; j < 80; ++j) {                      // argmax on raw
                const float x = p[(size_t)(5 + j) * HWn];       // (sigmoid monotone)
                if (x > m) { m = x; cp = j; }
            }
            const float cc    = sig_(m);
            const float conf  = sig_(tc);
            const float score = __fmul_rn(conf, cc);
            const float aw = anc[(6 + a) * 2 + 0] * 0.125f;
            const float ah = anc[(6 + a) * 2 + 1] * 0.125f;
            const float cx = (sig_(tx) + (float)(pos % Wd)) / 52.0f;
            const float cy = (sig_(ty) + (float)(pos / Wd)) / 52.0f;
            const float bw = expf(tw) * aw / 52.0f;
            const float bh = expf(th) * ah / 52.0f;
            const float hw = __fmul_rn(bw, 0.5f);
            const float hh = __fmul_rn(bh, 0.5f);
            const float x1 = __fsub_rn(cx, hw), y1 = __fsub_rn(cy, hh);
            const float x2 = __fadd_rn(cx, hw), y2 = __fadd_rn(cy, hh);
            float4* w4 = (float4*)ws;
            w4[2 * n + 0] = make_float4(x1, y1, x2, y2);
            w4[2 * n + 1] = make_float4(conf, cc, (float)cp, 0.0f);
            if (score >= 0.5f) {
                const int slot = atomicAdd(&meta[0], 1);
                ks[slot] = score;
                ki[slot] = n;
            }
        }
    }
    __threadfence_block();
    __syncthreads();
    const int V = meta[0];
    int P2 = 1; while (P2 < V) P2 <<= 1;

    // ---- bitonic sort: (score desc, index asc) — deterministic ----
    for (int k = 2; k <= P2; k <<= 1) {
        for (int j = k >> 1; j > 0; j >>= 1) {
            for (int i = tid; i < P2; i += NTHREADS) {
                const int l = i ^ j;
                if (l > i) {
                    const float si = ks[i], sl = ks[l];
                    const int   ni = ki[i], nl = ki[l];
                    const bool bli = (sl > si) || (sl == si && nl < ni); // l precedes i
                    const bool bil = (si > sl) || (si == sl && ni < nl); // i precedes l
                    const bool up  = ((i & k) == 0);
                    if (up ? bli : bil) {
                        ks[i] = sl; ks[l] = si;
                        ki[i] = nl; ki[l] = ni;
                    }
                }
            }
            __syncthreads();
        }
    }

    // ---- greedy walk (wave 0): keep iff IoU<=0.4 vs all kept winners ----
    if (tid < 64) {
        int nk = 0;
        const float4* w4 = (const float4*)ws;
        for (int p = 0; p < V && nk < 100; ++p) {
            const int n = ki[p];
            const float4 bx = w4[2 * n + 0];     // corners x1,y1,x2,y2
            const float4 mt = w4[2 * n + 1];     // conf, class_conf, class_pred
            const float off = __fmul_rn(mt.z, 4096.0f);
            const float ox1 = __fadd_rn(bx.x, off);
            const float oy1 = __fadd_rn(bx.y, off);
            const float ox2 = __fadd_rn(bx.z, off);
            const float oy2 = __fadd_rn(bx.w, off);
            bool sup = false;
            for (int t = tid; t < nk; t += 64) {
                const float kx1 = kept[4 * t], ky1 = kept[4 * t + 1];
                const float kx2 = kept[4 * t + 2], ky2 = kept[4 * t + 3];
                const float ltx = fmaxf(kx1, ox1), lty = fmaxf(ky1, oy1);
                const float rbx = fminf(kx2, ox2), rby = fminf(ky2, oy2);
                const float iw = fmaxf(__fsub_rn(rbx, ltx), 0.0f);
                const float ih = fmaxf(__fsub_rn(rby, lty), 0.0f);
                const float inter = __fmul_rn(iw, ih);
                const float a1 = __fmul_rn(__fsub_rn(kx2, kx1), __fsub_rn(ky2, ky1));
                const float a2 = __fmul_rn(__fsub_rn(ox2, ox1), __fsub_rn(oy2, oy1));
                const float den = __fadd_rn(__fsub_rn(__fadd_rn(a1, a2), inter), 1e-9f);
                const float iou = inter / den;
                if (iou > 0.4f) sup = true;
            }
            if (__ballot(sup) == 0ULL) {
                if (tid == 0) {
                    kept[4 * nk]     = ox1;
                    kept[4 * nk + 1] = oy1;
                    kept[4 * nk + 2] = ox2;
                    kept[4 * nk + 3] = oy2;
                    float* dr = detstage + nk * 7;
                    dr[0] = __fmul_rn(bx.y, 416.0f);   // y1*416
                    dr[1] = __fmul_rn(bx.x, 416.0f);   // x1*416
                    dr[2] = __fmul_rn(bx.w, 416.0f);   // y2*416
                    dr[3] = __fmul_rn(bx.z, 416.0f);   // x2*416
                    dr[4] = mt.x;                      // conf
                    dr[5] = mt.y;                      // class_conf
                    dr[6] = mt.z;                      // class_pred
                }
                ++nk;
            }
        }
        if (tid == 0) meta[1] = nk;
    }
    __syncthreads();

    // ---- write det: staged rows, zeros for rows >= nk (flag==0 rows) ----
    const int nk = meta[1];
    for (int i = tid; i < 100 * 7; i += NTHREADS) {
        out[OUT_DEC + i] = (i < nk * 7) ? detstage[i] : 0.0f;
    }
}

extern "C" void kernel_launch(void* const* d_in, const int* in_sizes, int n_in,
                              void* d_out, int out_size, void* d_ws, size_t ws_size,
                              hipStream_t stream) {
    const float* in  = (const float*)d_in[0];
    const float* anc = (const float*)d_in[1];
    float* out = (float*)d_out;
    float* ws  = (float*)d_ws;
    const size_t shmem = (size_t)(ATT * PITCH) * sizeof(float);   // 71,060 B
    hipLaunchKernelGGL(yolo_fused, dim3(DEC_BLOCKS + 1), dim3(NTHREADS),
                       shmem, stream, in, anc, out, ws);
}

// Round 2
// 279.154 us; speedup vs baseline: 1.2236x; 1.2236x over previous
//
#include <hip/hip_runtime.h>
#include <math.h>

#define NTHREADS 1024

constexpr int An = 3;
constexpr int Wd = 52;
constexpr int HWn = 2704;        // 52*52
constexpr int ATT = 85;
constexpr int CH = 208;          // 4 grid rows per decode tile
constexpr int PITCH = 209;       // odd -> LDS bank stride 17, conflict-free
constexpr int CHUNKS = 13;       // 2704 / 208
constexpr int BAn = 96;          // 32 batches * 3 anchors
constexpr int DEC_BLOCKS = BAn * CHUNKS;   // 1248
constexpr int NC = An * HWn;     // 8112 candidates (batch 0)
constexpr int NSORT = 8192;
constexpr int OUT_DEC = 32 * NC * ATT;     // 22064640 floats (decode output)
constexpr float NEGV = -1.0e9f;

__device__ __forceinline__ float sig_(float x) {
    return 1.0f / (1.0f + expf(-x));
}

__global__ void __launch_bounds__(NTHREADS)
yolo_fused(const float* __restrict__ in, const float* __restrict__ anc,
           float* __restrict__ out, float* __restrict__ ws)
{
    extern __shared__ float smem[];
    const int tid = threadIdx.x;

    if (blockIdx.x != 0) {
        // ======================= decode =======================
        const int bi    = (int)blockIdx.x - 1;
        const int chunk = bi % CHUNKS;
        const int ba    = bi / CHUNKS;
        const int a     = ba % An;
        const float anc_w = anc[(6 + a) * 2 + 0] * 0.125f;
        const float anc_h = anc[(6 + a) * 2 + 1] * 0.125f;
        const int pos0  = chunk * CH;
        const float* src = in + (size_t)ba * 85 * HWn + pos0;

        for (int i = tid; i < ATT * CH; i += NTHREADS) {
            const int attr = i / CH;
            const int p    = i - attr * CH;
            const int pos  = pos0 + p;
            const float x  = src[(size_t)attr * HWn + p];
            float v;
            if (attr >= 4)      v = sig_(x);
            else if (attr == 0) v = (sig_(x) + (float)(pos % Wd)) / 52.0f;
            else if (attr == 1) v = (sig_(x) + (float)(pos / Wd)) / 52.0f;
            else if (attr == 2) v = expf(x) * anc_w / 52.0f;
            else                v = expf(x) * anc_h / 52.0f;
            smem[attr * PITCH + p] = v;
        }
        __syncthreads();

        float* dst = out + ((size_t)ba * HWn + pos0) * ATT;
        for (int f = tid; f < CH * ATT; f += NTHREADS) {
            const int p    = f / ATT;
            const int attr = f - p * ATT;
            dst[f] = smem[attr * PITCH + p];
        }
        return;
    }

    // ======================= NMS (block 0, batch 0) =======================
    float* ks       = smem;                         // [8192] scores
    int*   ki       = (int*)(smem + NSORT);         // [8192] candidate index
    float* kept     = smem + 2 * NSORT;             // [100*4] kept oboxes
    float* detstage = smem + 2 * NSORT + 416;       // [100*7] staged det rows
    int*   meta     = (int*)(smem + 2 * NSORT + 416 + 704); // [0]=V, [1]=nk

    for (int i = tid; i < NSORT; i += NTHREADS) { ks[i] = NEGV; ki[i] = i; }
    if (tid == 0) meta[0] = 0;
    __syncthreads();

    // ---- prep: compute score/corners/class per candidate, payload -> ws ----
    for (int k = 0; k < 8; ++k) {
        const int n = tid + k * NTHREADS;
        if (n < NC) {
            const int a   = n / HWn;
            const int pos = n - a * HWn;
            const float* p = in + (size_t)a * 85 * HWn + pos;  // batch 0
            const float tx = p[0];
            const float ty = p[HWn];
            const float tw = p[2 * HWn];
            const float th = p[3 * HWn];
            const float tc = p[4 * HWn];
            float m = -3.0e38f; int cp = 0;
            for (int j = 0; j < 80; ++j) {                      // argmax on raw
                const float x = p[(size_t)(5 + j) * HWn];       // (sigmoid monotone)
                if (x > m) { m = x; cp = j; }
            }
            const float cc    = sig_(m);
            const float conf  = sig_(tc);
            const float score = __fmul_rn(conf, cc);
            const float aw = anc[(6 + a) * 2 + 0] * 0.125f;
            const float ah = anc[(6 + a) * 2 + 1] * 0.125f;
            const float cx = (sig_(tx) + (float)(pos % Wd)) / 52.0f;
            const float cy = (sig_(ty) + (float)(pos / Wd)) / 52.0f;
            const float bw = expf(tw) * aw / 52.0f;
            const float bh = expf(th) * ah / 52.0f;
            const float hw = __fmul_rn(bw, 0.5f);
            const float hh = __fmul_rn(bh, 0.5f);
            const float x1 = __fsub_rn(cx, hw), y1 = __fsub_rn(cy, hh);
            const float x2 = __fadd_rn(cx, hw), y2 = __fadd_rn(cy, hh);
            float4* w4 = (float4*)ws;
            w4[2 * n + 0] = make_float4(x1, y1, x2, y2);
            w4[2 * n + 1] = make_float4(conf, cc, (float)cp, 0.0f);
            if (score >= 0.5f) {
                const int slot = atomicAdd(&meta[0], 1);
                ks[slot] = score;
                ki[slot] = n;
            }
        }
    }
    __threadfence_block();
    __syncthreads();
    const int V = meta[0];
    int P2 = 1; while (P2 < V) P2 <<= 1;

    // ---- bitonic sort: (score desc, index asc) — deterministic ----
    for (int k = 2; k <= P2; k <<= 1) {
        for (int j = k >> 1; j > 0; j >>= 1) {
            for (int i = tid; i < P2; i += NTHREADS) {
                const int l = i ^ j;
                if (l > i) {
                    const float si = ks[i], sl = ks[l];
                    const int   ni = ki[i], nl = ki[l];
                    const bool bli = (sl > si) || (sl == si && nl < ni);
                    const bool bil = (si > sl) || (si == sl && ni < nl);
                    const bool up  = ((i & k) == 0);
                    if (up ? bli : bil) {
                        ks[i] = sl; ks[l] = si;
                        ki[i] = nl; ki[l] = ni;
                    }
                }
            }
            __syncthreads();
        }
    }

    // ---- greedy walk, 64-wide batches (wave 0 only) ----
    if (tid < 64) {
        const float4* w4 = (const float4*)ws;
        float4* keptv = (float4*)kept;
        int nk = 0;

        // preload batch 0 payload
        float cx1 = 0, cy1 = 0, cx2 = 0, cy2 = 0, mconf = 0, mcc = 0, mcp = 0;
        bool act = (tid < V);
        if (act) {
            const int n = ki[tid];
            const float4 bx = w4[2 * n], mt = w4[2 * n + 1];
            cx1 = bx.x; cy1 = bx.y; cx2 = bx.z; cy2 = bx.w;
            mconf = mt.x; mcc = mt.y; mcp = mt.z;
        }

        for (int p0 = 0; p0 < V && nk < 100; p0 += 64) {
            // software-pipeline: issue next batch's scattered gathers now
            float nx1 = 0, ny1 = 0, nx2 = 0, ny2 = 0, nco = 0, ncc = 0, ncp = 0;
            const bool actn = (p0 + 64 + tid) < V;
            if (actn) {
                const int n = ki[p0 + 64 + tid];
                const float4 bx = w4[2 * n], mt = w4[2 * n + 1];
                nx1 = bx.x; ny1 = bx.y; nx2 = bx.z; ny2 = bx.w;
                nco = mt.x; ncc = mt.y; ncp = mt.z;
            }

            // class-offset box + area (computed from offset corners, as ref)
            const float off = __fmul_rn(mcp, 4096.0f);
            const float ox1 = __fadd_rn(cx1, off);
            const float oy1 = __fadd_rn(cy1, off);
            const float ox2 = __fadd_rn(cx2, off);
            const float oy2 = __fadd_rn(cy2, off);
            const float aC  = __fmul_rn(__fsub_rn(ox2, ox1), __fsub_rn(oy2, oy1));

            // parallel test vs all previously-kept boxes
            bool sup = !act;
            for (int t = 0; t < nk; ++t) {
                const float4 kb = keptv[t];                 // broadcast LDS read
                const float ltx = fmaxf(kb.x, ox1), lty = fmaxf(kb.y, oy1);
                const float rbx = fminf(kb.z, ox2), rby = fminf(kb.w, oy2);
                const float iw = fmaxf(__fsub_rn(rbx, ltx), 0.0f);
                const float ih = fmaxf(__fsub_rn(rby, lty), 0.0f);
                const float inter = __fmul_rn(iw, ih);
                const float aK = __fmul_rn(__fsub_rn(kb.z, kb.x), __fsub_rn(kb.w, kb.y));
                const float den = __fadd_rn(__fsub_rn(__fadd_rn(aK, aC), inter), 1e-9f);
                if (inter / den > 0.4f) sup = true;
            }

            // serial in-batch resolve: lowest unsuppressed lane = next greedy pick
            unsigned long long rem = __ballot(!sup);
            while (rem != 0ULL && nk < 100) {
                const int w = __ffsll(rem) - 1;
                const float wx1 = __shfl(ox1, w), wy1 = __shfl(oy1, w);
                const float wx2 = __shfl(ox2, w), wy2 = __shfl(oy2, w);
                const float aW  = __shfl(aC, w);
                if (tid == w) {
                    keptv[nk] = make_float4(ox1, oy1, ox2, oy2);
                    float* dr = detstage + nk * 7;
                    // exact midpoint round-trip as the reference epilogue
                    const float xm  = __fmul_rn(__fadd_rn(cx1, cx2), 0.5f);
                    const float ym  = __fmul_rn(__fadd_rn(cy1, cy2), 0.5f);
                    const float hw2 = __fmul_rn(__fsub_rn(cx2, cx1), 0.5f);
                    const float hh2 = __fmul_rn(__fsub_rn(cy2, cy1), 0.5f);
                    dr[0] = __fmul_rn(__fsub_rn(ym, hh2), 416.0f);
                    dr[1] = __fmul_rn(__fsub_rn(xm, hw2), 416.0f);
                    dr[2] = __fmul_rn(__fadd_rn(ym, hh2), 416.0f);
                    dr[3] = __fmul_rn(__fadd_rn(xm, hw2), 416.0f);
                    dr[4] = mconf; dr[5] = mcc; dr[6] = mcp;
                }
                ++nk;
                if (!sup && tid > w) {
                    const float ltx = fmaxf(wx1, ox1), lty = fmaxf(wy1, oy1);
                    const float rbx = fminf(wx2, ox2), rby = fminf(wy2, oy2);
                    const float iw = fmaxf(__fsub_rn(rbx, ltx), 0.0f);
                    const float ih = fmaxf(__fsub_rn(rby, lty), 0.0f);
                    const float inter = __fmul_rn(iw, ih);
                    const float den = __fadd_rn(__fsub_rn(__fadd_rn(aW, aC), inter), 1e-9f);
                    if (inter / den > 0.4f) sup = true;
                }
                rem = __ballot(!sup && tid > w);
            }

            // rotate pipeline registers
            cx1 = nx1; cy1 = ny1; cx2 = nx2; cy2 = ny2;
            mconf = nco; mcc = ncc; mcp = ncp;
            act = actn;
        }
        if (tid == 0) meta[1] = nk;
    }
    __syncthreads();

    // ---- write det: staged rows, zeros for rows >= nk ----
    const int nk = meta[1];
    for (int i = tid; i < 100 * 7; i += NTHREADS) {
        out[OUT_DEC + i] = (i < nk * 7) ? detstage[i] : 0.0f;
    }
}

extern "C" void kernel_launch(void* const* d_in, const int* in_sizes, int n_in,
                              void* d_out, int out_size, void* d_ws, size_t ws_size,
                              hipStream_t stream) {
    const float* in  = (const float*)d_in[0];
    const float* anc = (const float*)d_in[1];
    float* out = (float*)d_out;
    float* ws  = (float*)d_ws;
    const size_t shmem = (size_t)(ATT * PITCH) * sizeof(float);   // 71,060 B
    hipLaunchKernelGGL(yolo_fused, dim3(DEC_BLOCKS + 1), dim3(NTHREADS),
                       shmem, stream, in, anc, out, ws);
}

// Round 3
// 273.745 us; speedup vs baseline: 1.2478x; 1.0198x over previous
//
#include <hip/hip_runtime.h>
#include <math.h>

constexpr int An = 3;
constexpr int Wd = 52;
constexpr int HWn = 2704;        // 52*52
constexpr int ATT = 85;
constexpr int CH = 208;          // 4 grid rows per decode tile
constexpr int PITCH = 209;       // odd -> LDS bank stride 17, conflict-free
constexpr int CHUNKS = 13;       // 2704 / 208
constexpr int DEC_BLOCKS = 96 * CHUNKS;    // 1248
constexpr int NC = An * HWn;     // 8112 candidates (batch 0)
constexpr int NSORT = 8192;
constexpr int OUT_DEC = 32 * NC * ATT;     // 22064640 floats (decode output)
constexpr float NEGV = -1.0e9f;
constexpr int WS_SCORE_OFF = 65536;        // floats; payload = 8112*8 floats before it

__device__ __forceinline__ float sig_(float x) {
    return 1.0f / (1.0f + expf(-x));
}

// ==================== kernel 1: prep (candidate scoring) ====================
__global__ void __launch_bounds__(128)
yolo_prep(const float* __restrict__ in, const float* __restrict__ anc,
          float* __restrict__ ws)
{
    const int n = blockIdx.x * 128 + threadIdx.x;
    if (n >= NC) return;
    const int a   = n / HWn;
    const int pos = n - a * HWn;
    const float* p = in + (size_t)a * 85 * HWn + pos;   // batch 0

    const float tx = p[0];
    const float ty = p[HWn];
    const float tw = p[2 * HWn];
    const float th = p[3 * HWn];
    const float tc = p[4 * HWn];

    // argmax over 80 raw class logits (sigmoid monotone), 16 loads in flight
    float m = -3.0e38f; int cp = 0;
    #pragma unroll
    for (int j0 = 0; j0 < 80; j0 += 16) {
        float v[16];
        #pragma unroll
        for (int u = 0; u < 16; ++u) v[u] = p[(size_t)(5 + j0 + u) * HWn];
        #pragma unroll
        for (int u = 0; u < 16; ++u) {
            if (v[u] > m) { m = v[u]; cp = j0 + u; }
        }
    }

    const float cc    = sig_(m);
    const float conf  = sig_(tc);
    const float score = __fmul_rn(conf, cc);
    const float aw = anc[(6 + a) * 2 + 0] * 0.125f;
    const float ah = anc[(6 + a) * 2 + 1] * 0.125f;
    const float cx = (sig_(tx) + (float)(pos % Wd)) / 52.0f;
    const float cy = (sig_(ty) + (float)(pos / Wd)) / 52.0f;
    const float bw = expf(tw) * aw / 52.0f;
    const float bh = expf(th) * ah / 52.0f;
    const float hw = __fmul_rn(bw, 0.5f);
    const float hh = __fmul_rn(bh, 0.5f);
    float4* w4 = (float4*)ws;
    w4[2 * n + 0] = make_float4(__fsub_rn(cx, hw), __fsub_rn(cy, hh),
                                __fadd_rn(cx, hw), __fadd_rn(cy, hh));
    w4[2 * n + 1] = make_float4(conf, cc, (float)cp, 0.0f);
    ws[WS_SCORE_OFF + n] = score;
}

// ==================== kernel 2: NMS (sort + greedy walk) ====================
__global__ void __launch_bounds__(1024)
yolo_nms(const float* __restrict__ ws, float* __restrict__ out)
{
    __shared__ unsigned long long keys[NSORT];   // 64 KB
    __shared__ float kept[100 * 4];
    __shared__ float detstage[100 * 7];
    __shared__ int   meta[2];
    const int tid = threadIdx.x;
    const unsigned lane = tid & 63;

    if (tid == 0) meta[0] = 0;
    __syncthreads();

    // ---- compact valid candidates into packed keys (wave-aggregated) ----
    const float* wscore = ws + WS_SCORE_OFF;
    for (int k = 0; k < 8; ++k) {
        const int n = tid + k * 1024;
        const float s = (n < NC) ? wscore[n] : NEGV;
        const bool valid = (s >= 0.5f);
        const unsigned long long mask = __ballot(valid);
        if (mask != 0ULL) {
            const int leader = __ffsll((long long)mask) - 1;
            int base = 0;
            if ((int)lane == leader) base = atomicAdd(&meta[0], __popcll(mask));
            base = __shfl(base, leader);
            if (valid) {
                const int slot = base +
                    __popcll(mask & ((1ULL << lane) - 1ULL));
                keys[slot] =
                    ((unsigned long long)(0xFFFFFFFFu - __float_as_uint(s)) << 32)
                    | (unsigned)n;
            }
        }
    }
    __syncthreads();
    const int V = meta[0];
    int P2 = 1; while (P2 < V) P2 <<= 1;

    for (int i = V + tid; i < P2; i += 1024) keys[i] = ~0ULL;   // pad
    __syncthreads();

    // ---- bitonic ascending: (score desc, index asc) ----
    for (int k = 2; k <= P2; k <<= 1) {
        for (int j = k >> 1; j > 0; j >>= 1) {
            for (int i = tid; i < P2; i += 1024) {
                const int l = i ^ j;
                if (l > i) {
                    const unsigned long long a = keys[i], b = keys[l];
                    const bool up = ((i & k) == 0);
                    if (up ? (b < a) : (a < b)) { keys[i] = b; keys[l] = a; }
                }
            }
            __syncthreads();
        }
    }

    // ---- greedy walk, 64-wide batches (wave 0 only) ----
    if (tid < 64) {
        const float4* w4 = (const float4*)ws;
        float4* keptv = (float4*)kept;
        int nk = 0;

        float cx1 = 0, cy1 = 0, cx2 = 0, cy2 = 0, mconf = 0, mcc = 0, mcp = 0;
        bool act = (tid < V);
        if (act) {
            const int n = (int)(keys[tid] & 0xFFFFFFFFu);
            const float4 bx = w4[2 * n], mt = w4[2 * n + 1];
            cx1 = bx.x; cy1 = bx.y; cx2 = bx.z; cy2 = bx.w;
            mconf = mt.x; mcc = mt.y; mcp = mt.z;
        }

        for (int p0 = 0; p0 < V && nk < 100; p0 += 64) {
            // pipeline next batch's scattered gathers
            float nx1 = 0, ny1 = 0, nx2 = 0, ny2 = 0, nco = 0, ncc = 0, ncp = 0;
            const bool actn = (p0 + 64 + tid) < V;
            if (actn) {
                const int n = (int)(keys[p0 + 64 + tid] & 0xFFFFFFFFu);
                const float4 bx = w4[2 * n], mt = w4[2 * n + 1];
                nx1 = bx.x; ny1 = bx.y; nx2 = bx.z; ny2 = bx.w;
                nco = mt.x; ncc = mt.y; ncp = mt.z;
            }

            const float off = __fmul_rn(mcp, 4096.0f);
            const float ox1 = __fadd_rn(cx1, off);
            const float oy1 = __fadd_rn(cy1, off);
            const float ox2 = __fadd_rn(cx2, off);
            const float oy2 = __fadd_rn(cy2, off);
            const float aC  = __fmul_rn(__fsub_rn(ox2, ox1), __fsub_rn(oy2, oy1));

            bool sup = !act;
            for (int t = 0; t < nk; ++t) {
                const float4 kb = keptv[t];                 // broadcast LDS read
                const float ltx = fmaxf(kb.x, ox1), lty = fmaxf(kb.y, oy1);
                const float rbx = fminf(kb.z, ox2), rby = fminf(kb.w, oy2);
                const float iw = fmaxf(__fsub_rn(rbx, ltx), 0.0f);
                const float ih = fmaxf(__fsub_rn(rby, lty), 0.0f);
                const float inter = __fmul_rn(iw, ih);
                const float aK = __fmul_rn(__fsub_rn(kb.z, kb.x), __fsub_rn(kb.w, kb.y));
                const float den = __fadd_rn(__fsub_rn(__fadd_rn(aK, aC), inter), 1e-9f);
                if (inter / den > 0.4f) sup = true;
            }

            unsigned long long rem = __ballot(!sup);
            while (rem != 0ULL && nk < 100) {
                const int w = __ffsll((long long)rem) - 1;
                const float wx1 = __shfl(ox1, w), wy1 = __shfl(oy1, w);
                const float wx2 = __shfl(ox2, w), wy2 = __shfl(oy2, w);
                const float aW  = __shfl(aC, w);
                if (tid == w) {
                    keptv[nk] = make_float4(ox1, oy1, ox2, oy2);
                    float* dr = detstage + nk * 7;
                    const float xm  = __fmul_rn(__fadd_rn(cx1, cx2), 0.5f);
                    const float ym  = __fmul_rn(__fadd_rn(cy1, cy2), 0.5f);
                    const float hw2 = __fmul_rn(__fsub_rn(cx2, cx1), 0.5f);
                    const float hh2 = __fmul_rn(__fsub_rn(cy2, cy1), 0.5f);
                    dr[0] = __fmul_rn(__fsub_rn(ym, hh2), 416.0f);
                    dr[1] = __fmul_rn(__fsub_rn(xm, hw2), 416.0f);
                    dr[2] = __fmul_rn(__fadd_rn(ym, hh2), 416.0f);
                    dr[3] = __fmul_rn(__fadd_rn(xm, hw2), 416.0f);
                    dr[4] = mconf; dr[5] = mcc; dr[6] = mcp;
                }
                ++nk;
                if (!sup && tid > w) {
                    const float ltx = fmaxf(wx1, ox1), lty = fmaxf(wy1, oy1);
                    const float rbx = fminf(wx2, ox2), rby = fminf(wy2, oy2);
                    const float iw = fmaxf(__fsub_rn(rbx, ltx), 0.0f);
                    const float ih = fmaxf(__fsub_rn(rby, lty), 0.0f);
                    const float inter = __fmul_rn(iw, ih);
                    const float den = __fadd_rn(__fsub_rn(__fadd_rn(aW, aC), inter), 1e-9f);
                    if (inter / den > 0.4f) sup = true;
                }
                rem = __ballot(!sup && tid > w);
            }

            cx1 = nx1; cy1 = ny1; cx2 = nx2; cy2 = ny2;
            mconf = nco; mcc = ncc; mcp = ncp;
            act = actn;
        }
        if (tid == 0) meta[1] = nk;
    }
    __syncthreads();

    const int nk = meta[1];
    for (int i = tid; i < 100 * 7; i += 1024) {
        out[OUT_DEC + i] = (i < nk * 7) ? detstage[i] : 0.0f;
    }
}

// ==================== kernel 3: decode ====================
__global__ void __launch_bounds__(1024)
yolo_decode(const float* __restrict__ in, const float* __restrict__ anc,
            float* __restrict__ out)
{
    extern __shared__ float smem[];
    const int tid = threadIdx.x;
    const int bi    = (int)blockIdx.x;
    const int chunk = bi % CHUNKS;
    const int ba    = bi / CHUNKS;
    const int a     = ba % An;
    const float anc_w = anc[(6 + a) * 2 + 0] * 0.125f;
    const float anc_h = anc[(6 + a) * 2 + 1] * 0.125f;
    const int pos0  = chunk * CH;
    const float* src = in + (size_t)ba * 85 * HWn + pos0;

    for (int i = tid; i < ATT * CH; i += 1024) {
        const int attr = i / CH;
        const int p    = i - attr * CH;
        const int pos  = pos0 + p;
        const float x  = src[(size_t)attr * HWn + p];
        float v;
        if (attr >= 4)      v = sig_(x);
        else if (attr == 0) v = (sig_(x) + (float)(pos % Wd)) / 52.0f;
        else if (attr == 1) v = (sig_(x) + (float)(pos / Wd)) / 52.0f;
        else if (attr == 2) v = expf(x) * anc_w / 52.0f;
        else                v = expf(x) * anc_h / 52.0f;
        smem[attr * PITCH + p] = v;
    }
    __syncthreads();

    float* dst = out + ((size_t)ba * HWn + pos0) * ATT;
    for (int f = tid; f < CH * ATT; f += 1024) {
        const int p    = f / ATT;
        const int attr = f - p * ATT;
        dst[f] = smem[attr * PITCH + p];
    }
}

extern "C" void kernel_launch(void* const* d_in, const int* in_sizes, int n_in,
                              void* d_out, int out_size, void* d_ws, size_t ws_size,
                              hipStream_t stream) {
    const float* in  = (const float*)d_in[0];
    const float* anc = (const float*)d_in[1];
    float* out = (float*)d_out;
    float* ws  = (float*)d_ws;

    hipLaunchKernelGGL(yolo_prep, dim3((NC + 127) / 128), dim3(128), 0, stream,
                       in, anc, ws);
    hipLaunchKernelGGL(yolo_nms, dim3(1), dim3(1024), 0, stream, ws, out);
    const size_t shmem = (size_t)(ATT * PITCH) * sizeof(float);   // 71,060 B
    hipLaunchKernelGGL(yolo_decode, dim3(DEC_BLOCKS), dim3(1024), shmem, stream,
                       in, anc, out);
}

// Round 4
// 235.553 us; speedup vs baseline: 1.4501x; 1.1621x over previous
//
#include <hip/hip_runtime.h>
#include <math.h>

constexpr int An = 3;
constexpr int Wd = 52;
constexpr int HWn = 2704;        // 52*52
constexpr int ATT = 85;
constexpr int CH = 208;          // 4 grid rows per decode tile
constexpr int PITCH = 212;       // multiple of 4 -> 16B-aligned b128 LDS writes
constexpr int CHUNKS = 13;       // 2704 / 208
constexpr int DEC_BLOCKS = 96 * CHUNKS;    // 1248
constexpr int NC = An * HWn;     // 8112 candidates (batch 0)
constexpr int OUT_DEC = 32 * NC * ATT;     // 22064640 floats (decode output)
constexpr float NEGV = -1.0e9f;
constexpr int WS_SCORE_OFF = 65536;        // floats; payload = 8112*8 floats before it
constexpr size_t DEC_LDS = (size_t)ATT * PITCH * sizeof(float);   // 72,080 B

__device__ __forceinline__ float sig_(float x) {
    return 1.0f / (1.0f + expf(-x));
}

// ==================== kernel 1: prep (candidate scoring) ====================
__global__ void __launch_bounds__(128)
yolo_prep(const float* __restrict__ in, const float* __restrict__ anc,
          float* __restrict__ ws)
{
    const int n = blockIdx.x * 128 + threadIdx.x;
    if (n >= NC) return;
    const int a   = n / HWn;
    const int pos = n - a * HWn;
    const float* p = in + (size_t)a * 85 * HWn + pos;   // batch 0

    const float tx = p[0];
    const float ty = p[HWn];
    const float tw = p[2 * HWn];
    const float th = p[3 * HWn];
    const float tc = p[4 * HWn];

    // argmax over 80 raw class logits (sigmoid monotone), 16 loads in flight
    float m = -3.0e38f; int cp = 0;
    #pragma unroll
    for (int j0 = 0; j0 < 80; j0 += 16) {
        float v[16];
        #pragma unroll
        for (int u = 0; u < 16; ++u) v[u] = p[(size_t)(5 + j0 + u) * HWn];
        #pragma unroll
        for (int u = 0; u < 16; ++u) {
            if (v[u] > m) { m = v[u]; cp = j0 + u; }
        }
    }

    const float cc    = sig_(m);
    const float conf  = sig_(tc);
    const float score = __fmul_rn(conf, cc);
    const float aw = anc[(6 + a) * 2 + 0] * 0.125f;
    const float ah = anc[(6 + a) * 2 + 1] * 0.125f;
    const float cx = (sig_(tx) + (float)(pos % Wd)) / 52.0f;
    const float cy = (sig_(ty) + (float)(pos / Wd)) / 52.0f;
    const float bw = expf(tw) * aw / 52.0f;
    const float bh = expf(th) * ah / 52.0f;
    const float hw = __fmul_rn(bw, 0.5f);
    const float hh = __fmul_rn(bh, 0.5f);
    float4* w4 = (float4*)ws;
    w4[2 * n + 0] = make_float4(__fsub_rn(cx, hw), __fsub_rn(cy, hh),
                                __fadd_rn(cx, hw), __fadd_rn(cy, hh));
    w4[2 * n + 1] = make_float4(conf, cc, (float)cp, 0.0f);
    ws[WS_SCORE_OFF + n] = score;
}

// ============ kernel 2 (fused): block 0 = NMS, blocks 1.. = decode ============
__global__ void __launch_bounds__(1024)
yolo_fused(const float* __restrict__ in, const float* __restrict__ anc,
           float* __restrict__ out, const float* __restrict__ ws)
{
    extern __shared__ float dynsm[];
    const int tid = threadIdx.x;

    if (blockIdx.x != 0) {
        // ======================= decode (vectorized) =======================
        const int bi    = (int)blockIdx.x - 1;
        const int chunk = bi % CHUNKS;
        const int ba    = bi / CHUNKS;
        const int a     = ba % An;
        const float anc_w = anc[(6 + a) * 2 + 0] * 0.125f;
        const float anc_h = anc[(6 + a) * 2 + 1] * 0.125f;
        const int pos0  = chunk * CH;
        const float* src = in + (size_t)ba * 85 * HWn + pos0;
        const float gy0 = (float)(chunk * 4);

        // load phase: float4 global load, b128 LDS write (seq addrs, no conflict)
        for (int i = tid; i < ATT * 52; i += 1024) {
            const int attr = i / 52;
            const int q    = i - attr * 52;
            const float4 x = *(const float4*)(src + (size_t)attr * HWn + 4 * q);
            const float xs[4] = {x.x, x.y, x.z, x.w};
            float v[4];
            #pragma unroll
            for (int u = 0; u < 4; ++u) {
                const int pp = 4 * q + u;
                float val;
                if (attr >= 4)      val = sig_(xs[u]);
                else if (attr == 0) val = (sig_(xs[u]) + (float)(pp % 52)) / 52.0f;
                else if (attr == 1) val = (sig_(xs[u]) + (gy0 + (float)(pp / 52))) / 52.0f;
                else if (attr == 2) val = expf(xs[u]) * anc_w / 52.0f;
                else                val = expf(xs[u]) * anc_h / 52.0f;
                v[u] = val;
            }
            *(float4*)(dynsm + attr * PITCH + 4 * q) = make_float4(v[0], v[1], v[2], v[3]);
        }
        __syncthreads();

        // store phase: 4x b32 LDS reads (stride 212: 4-way, 1.58x), float4 store
        float* dst = out + ((size_t)ba * HWn + pos0) * ATT;
        for (int j = tid; j < ATT * 52; j += 1024) {
            const int f0 = 4 * j;
            float v[4];
            #pragma unroll
            for (int u = 0; u < 4; ++u) {
                const int g  = f0 + u;
                const int p  = g / 85;
                const int at = g - 85 * p;
                v[u] = dynsm[at * PITCH + p];
            }
            *(float4*)(dst + f0) = make_float4(v[0], v[1], v[2], v[3]);
        }
        return;
    }

    // ======================= NMS (block 0, batch 0) =======================
    // LDS carve (dynsm is 16B aligned): keys 64KB | kept 1.6KB | det 2.8KB | misc
    unsigned long long* keys = (unsigned long long*)dynsm;   // [8192]
    float* kept     = dynsm + 16384;          // 100*4
    float* detstage = kept + 400;             // 100*7
    float* winslot  = detstage + 700;         // 8 floats: box4 + area
    int*   wavemin  = (int*)(winslot + 8);    // 16
    int*   meta     = wavemin + 16;           // counters
    const int lane = tid & 63;
    const int wv   = tid >> 6;

    if (tid == 0) meta[0] = 0;
    __syncthreads();

    // ---- compact valid candidates into packed keys (wave-aggregated) ----
    const float* wscore = ws + WS_SCORE_OFF;
    for (int k = 0; k < 8; ++k) {
        const int n = tid + k * 1024;
        const float s = (n < NC) ? wscore[n] : NEGV;
        const bool valid = (s >= 0.5f);
        const unsigned long long mask = __ballot(valid);
        if (mask != 0ULL) {
            const int leader = __ffsll((long long)mask) - 1;
            int base = 0;
            if (lane == leader) base = atomicAdd(&meta[0], __popcll(mask));
            base = __shfl(base, leader);
            if (valid) {
                const int slot = base + __popcll(mask & ((1ULL << lane) - 1ULL));
                keys[slot] =
                    ((unsigned long long)(0xFFFFFFFFu - __float_as_uint(s)) << 32)
                    | (unsigned)n;
            }
        }
    }
    __syncthreads();
    const int V = meta[0];
    int P2 = 1; while (P2 < V) P2 <<= 1;
    for (int i = V + tid; i < P2; i += 1024) keys[i] = ~0ULL;   // pad
    __syncthreads();

    // ---- bitonic ascending, pair-indexed (no divergence waste) ----
    for (int k = 2; k <= P2; k <<= 1) {
        for (int j = k >> 1; j > 0; j >>= 1) {
            for (int idx = tid; idx < (P2 >> 1); idx += 1024) {
                const int i = ((idx & ~(j - 1)) << 1) | (idx & (j - 1));
                const int l = i | j;
                const unsigned long long a = keys[i], b = keys[l];
                const bool up = ((i & k) == 0);
                if (up ? (b < a) : (a < b)) { keys[i] = b; keys[l] = a; }
            }
            __syncthreads();
        }
    }

    // ---- block-parallel greedy walk: super-batches of 1024 candidates ----
    const float4* w4 = (const float4*)ws;
    float4* keptv = (float4*)kept;
    int nk = 0;
    for (int sb = 0; sb * 1024 < V && nk < 100; ++sb) {
        const int cidx = sb * 1024 + tid;
        const bool act = (cidx < V);
        float rx1 = 0, ry1 = 0, rx2 = 0, ry2 = 0, mconf = 0, mcc = 0, mcp = 0;
        float ox1 = 0, oy1 = 0, ox2 = 0, oy2 = 0, aC = 0;
        bool alive = act;
        if (act) {
            const int n = (int)(keys[cidx] & 0xFFFFFFFFu);
            const float4 bx = w4[2 * n], mt = w4[2 * n + 1];
            rx1 = bx.x; ry1 = bx.y; rx2 = bx.z; ry2 = bx.w;
            mconf = mt.x; mcc = mt.y; mcp = mt.z;
            const float off = __fmul_rn(mcp, 4096.0f);
            ox1 = __fadd_rn(rx1, off); oy1 = __fadd_rn(ry1, off);
            ox2 = __fadd_rn(rx2, off); oy2 = __fadd_rn(ry2, off);
            aC  = __fmul_rn(__fsub_rn(ox2, ox1), __fsub_rn(oy2, oy1));
            // snapshot test vs all kept so far (16-wave parallel)
            for (int t = 0; t < nk && alive; ++t) {
                const float4 kb = keptv[t];
                const float ltx = fmaxf(kb.x, ox1), lty = fmaxf(kb.y, oy1);
                const float rbx = fminf(kb.z, ox2), rby = fminf(kb.w, oy2);
                const float iw = fmaxf(__fsub_rn(rbx, ltx), 0.0f);
                const float ih = fmaxf(__fsub_rn(rby, lty), 0.0f);
                const float inter = __fmul_rn(iw, ih);
                const float aK = __fmul_rn(__fsub_rn(kb.z, kb.x), __fsub_rn(kb.w, kb.y));
                const float den = __fadd_rn(__fsub_rn(__fadd_rn(aK, aC), inter), 1e-9f);
                if (inter / den > 0.4f) alive = false;
            }
        }
        if (tid == 0) {   // dummy far-away winner: IoU vs anything = 0
            winslot[0] = 4e9f; winslot[1] = 4e9f; winslot[2] = 4e9f; winslot[3] = 4e9f;
            winslot[4] = 0.0f;
        }
        __syncthreads();

        // pick-one-per-round resolve
        while (true) {
            if (alive) {   // test vs last round's winner
                const float wx1 = winslot[0], wy1 = winslot[1];
                const float wx2 = winslot[2], wy2 = winslot[3], aW = winslot[4];
                const float ltx = fmaxf(wx1, ox1), lty = fmaxf(wy1, oy1);
                const float rbx = fminf(wx2, ox2), rby = fminf(wy2, oy2);
                const float iw = fmaxf(__fsub_rn(rbx, ltx), 0.0f);
                const float ih = fmaxf(__fsub_rn(rby, lty), 0.0f);
                const float inter = __fmul_rn(iw, ih);
                const float den = __fadd_rn(__fsub_rn(__fadd_rn(aW, aC), inter), 1e-9f);
                if (inter / den > 0.4f) alive = false;
            }
            const unsigned long long m = __ballot(alive);
            if (lane == 0)
                wavemin[wv] = m ? (wv * 64 + (__ffsll((long long)m) - 1)) : 0x7FFFFFFF;
            __syncthreads();
            int win = 0x7FFFFFFF;
            #pragma unroll
            for (int w = 0; w < 16; ++w) win = min(win, wavemin[w]);
            if (win == 0x7FFFFFFF) break;          // batch exhausted (uniform)
            if (tid == win) {
                winslot[0] = ox1; winslot[1] = oy1; winslot[2] = ox2; winslot[3] = oy2;
                winslot[4] = aC;
                keptv[nk] = make_float4(ox1, oy1, ox2, oy2);
                float* dr = detstage + nk * 7;
                const float xm  = __fmul_rn(__fadd_rn(rx1, rx2), 0.5f);
                const float ym  = __fmul_rn(__fadd_rn(ry1, ry2), 0.5f);
                const float hw2 = __fmul_rn(__fsub_rn(rx2, rx1), 0.5f);
                const float hh2 = __fmul_rn(__fsub_rn(ry2, ry1), 0.5f);
                dr[0] = __fmul_rn(__fsub_rn(ym, hh2), 416.0f);
                dr[1] = __fmul_rn(__fsub_rn(xm, hw2), 416.0f);
                dr[2] = __fmul_rn(__fadd_rn(ym, hh2), 416.0f);
                dr[3] = __fmul_rn(__fadd_rn(xm, hw2), 416.0f);
                dr[4] = mconf; dr[5] = mcc; dr[6] = mcp;
                alive = false;
            }
            __syncthreads();
            ++nk;
            if (nk == 100) break;                  // uniform
        }
    }
    __syncthreads();

    // ---- write det: staged rows, zeros for rows >= nk ----
    for (int i = tid; i < 100 * 7; i += 1024) {
        out[OUT_DEC + i] = (i < nk * 7) ? detstage[i] : 0.0f;
    }
}

extern "C" void kernel_launch(void* const* d_in, const int* in_sizes, int n_in,
                              void* d_out, int out_size, void* d_ws, size_t ws_size,
                              hipStream_t stream) {
    const float* in  = (const float*)d_in[0];
    const float* anc = (const float*)d_in[1];
    float* out = (float*)d_out;
    float* ws  = (float*)d_ws;

    hipLaunchKernelGGL(yolo_prep, dim3((NC + 127) / 128), dim3(128), 0, stream,
                       in, anc, ws);
    hipLaunchKernelGGL(yolo_fused, dim3(DEC_BLOCKS + 1), dim3(1024), DEC_LDS,
                       stream, in, anc, out, ws);
}